// Round 2
// baseline (348.750 us; speedup 1.0000x reference)
//
#include <hip/hip_runtime.h>
#include <hip/hip_bf16.h>
#include <stdint.h>

#define NSK   1000
#define EMB   256
#define BB    32
#define SS    2048
#define TILE  128
#define NJT   (SS / TILE)   // 16
#define BK    64            // K-chunk
#define KSTEPS (BK / 16)    // 4 mfma k-steps per chunk
#define NCHUNK (EMB / BK)   // 4

typedef __bf16 bf16x8 __attribute__((ext_vector_type(8)));
typedef float  f32x16 __attribute__((ext_vector_type(16)));
typedef float  f32x4  __attribute__((ext_vector_type(4)));

// bf16 table layout in workspace (element offsets)
#define OFF_AI 0                  // alpha_inter  [2000][256]
#define OFF_BI (2 * NSK * EMB)    // beta_inter   [2000][256]
#define OFF_AS (4 * NSK * EMB)    // alpha_skill  [1000][256]
#define OFF_BS (5 * NSK * EMB)    // beta_skill   [1000][256]
#define TOT_BF (6 * NSK * EMB)    // 1,536,000 elements = 3 MB

__global__ void cvt_tables(const float* __restrict__ ai, const float* __restrict__ bi,
                           const float* __restrict__ as_, const float* __restrict__ bs,
                           __bf16* __restrict__ ws) {
    int i = blockIdx.x * 256 + threadIdx.x;
    if (i >= TOT_BF) return;
    float v;
    if (i < OFF_AS) v = (i < OFF_BI) ? ai[i] : bi[i - OFF_BI];
    else            v = (i < OFF_BS) ? as_[i - OFF_AS] : bs[i - OFF_BS];
    ws[i] = (__bf16)v;
}

#define ASYNC16(g, l)                                                              \
    __builtin_amdgcn_global_load_lds((__attribute__((address_space(1))) void*)(g), \
                                     (__attribute__((address_space(3))) void*)(l), \
                                     16, 0, 0)

__global__ __launch_bounds__(256, 2) void hawkes_main(
    const int* __restrict__ skills, const int* __restrict__ problems,
    const int* __restrict__ times,  const int* __restrict__ labels,
    const float* __restrict__ pbW,  const float* __restrict__ sbW,
    const __bf16* __restrict__ tab,
    const float* __restrict__ aiW_f, const float* __restrict__ asW_f,
    float* __restrict__ out)
{
    // 4 matrices x 128 rows x 64 k, stored in MFMA-fragment order:
    // elem offset(mat, mblk, kstep, lane) = mat*8192 + (mblk*KSTEPS+kstep)*512 + lane*8
    __shared__ __align__(16) __bf16 sbuf[4 * TILE * BK];   // 64 KB
    __shared__ __align__(16) float  t_i[TILE];
    __shared__ __align__(16) float  t_j[TILE];
    __shared__ int   idx_i[TILE];
    __shared__ int   idx_j[TILE];
    __shared__ float colsum[TILE];

    const int bid = blockIdx.x;
    const int b   = bid & (BB - 1);
    const int jt  = (NJT - 1) - (bid >> 5);   // heavy j-tiles dispatched first
    const int j0  = jt * TILE;
    const int tid = threadIdx.x;
    const int l   = tid & 63;
    const int w   = tid >> 6;
    const int wi  = w >> 1, wj = w & 1;       // 2x2 wave quadrants of 128x128
    const int lane31 = l & 31;
    const int khalf  = l >> 5;

    // ---- j-side (fixed for this WG) ----
    if (tid < TILE) {
        int j = j0 + tid;
        idx_j[tid] = skills[b * SS + j];
        t_j[tid]   = (float)times[b * SS + j] / 1000.0f;
    }
    __syncthreads();

    float tj0 = t_j[wj * 64 + lane31];
    float tj1 = t_j[wj * 64 + 32 + lane31];
    float csum0 = 0.0f, csum1 = 0.0f;

    // per-wave staging assignment: wave w stages matrix w
    const __bf16* my_tab = (w == 0) ? (tab + OFF_AI)
                         : (w == 1) ? (tab + OFF_BI)
                         : (w == 2) ? (tab + OFF_AS)
                         :            (tab + OFF_BS);
    const int* my_idx = (w < 2) ? idx_i : idx_j;

    for (int it = 0; it <= jt; ++it) {
        const int i0   = it * TILE;
        const bool diag = (it == jt);

        __syncthreads();   // protect t_i/idx_i (read by previous elementwise / staging)
        if (tid < TILE) {
            int ii = i0 + tid;
            idx_i[tid] = skills[b * SS + ii] + labels[b * SS + ii] * NSK;
            t_i[tid]   = (float)times[b * SS + ii] / 1000.0f;
        }
        __syncthreads();

        f32x16 accA[2][2], accB[2][2];
#pragma unroll
        for (int mi = 0; mi < 2; ++mi)
#pragma unroll
            for (int nj = 0; nj < 2; ++nj) { accA[mi][nj] = 0.0f; accB[mi][nj] = 0.0f; }

        for (int c = 0; c < NCHUNK; ++c) {
            // ---- async stage: 16 x 1KB DMA per wave, fragment-order LDS ----
#pragma unroll
            for (int m = 0; m < 4; ++m) {
                int rowidx = my_idx[m * 32 + lane31];
                const __bf16* g = my_tab + (size_t)rowidx * EMB + c * BK + khalf * 8;
                __bf16* ldst = sbuf + w * (TILE * BK) + m * (KSTEPS * 512);
#pragma unroll
                for (int ks = 0; ks < KSTEPS; ++ks)
                    ASYNC16(g + ks * 16, ldst + ks * 512);
            }
            __syncthreads();   // staging complete (vmcnt drained by barrier)

            // ---- compute 4 k-steps ----
#pragma unroll
            for (int ks = 0; ks < KSTEPS; ++ks) {
                bf16x8 fa[2], fb[2], ga[2], gb[2];
#pragma unroll
                for (int mi = 0; mi < 2; ++mi) {
                    int mb = wi * 2 + mi;
                    fa[mi] = *(const bf16x8*)(sbuf + 0 * TILE * BK + (mb * KSTEPS + ks) * 512 + l * 8);
                    fb[mi] = *(const bf16x8*)(sbuf + 1 * TILE * BK + (mb * KSTEPS + ks) * 512 + l * 8);
                }
#pragma unroll
                for (int nj = 0; nj < 2; ++nj) {
                    int nb = wj * 2 + nj;
                    ga[nj] = *(const bf16x8*)(sbuf + 2 * TILE * BK + (nb * KSTEPS + ks) * 512 + l * 8);
                    gb[nj] = *(const bf16x8*)(sbuf + 3 * TILE * BK + (nb * KSTEPS + ks) * 512 + l * 8);
                }
#pragma unroll
                for (int mi = 0; mi < 2; ++mi)
#pragma unroll
                    for (int nj = 0; nj < 2; ++nj) {
                        accA[mi][nj] = __builtin_amdgcn_mfma_f32_32x32x16_bf16(fa[mi], ga[nj], accA[mi][nj], 0, 0, 0);
                        accB[mi][nj] = __builtin_amdgcn_mfma_f32_32x32x16_bf16(fb[mi], gb[nj], accB[mi][nj], 0, 0, 0);
                    }
            }
            __syncthreads();   // all waves done reading before next chunk overwrites
        }

        // ---- elementwise + column partial sums ----
        // C/D layout (32x32): col = lane&31, row = (reg&3) + 8*(reg>>2) + 4*(lane>>5)
#pragma unroll
        for (int mi = 0; mi < 2; ++mi) {
            const int rbase = (wi * 2 + mi) * 32 + 4 * khalf;
            f32x4 tiv[4];
#pragma unroll
            for (int q = 0; q < 4; ++q) tiv[q] = *(const f32x4*)(t_i + rbase + 8 * q);
#pragma unroll
            for (int nj = 0; nj < 2; ++nj) {
                const float tjv = (nj == 0) ? tj0 : tj1;
                const int   jl  = wj * 64 + nj * 32 + lane31;
                float s = 0.0f;
#pragma unroll
                for (int r = 0; r < 16; ++r) {
                    const int q = r >> 2, e = r & 3;
                    const int il = rbase + 8 * q + e;
                    if (diag && il >= jl) continue;   // strict upper triangle (i < j)
                    float d = fabsf(tiv[q][e] - tjv);
                    float alpha = accA[mi][nj][r];
                    if (d == 0.0f) {
                        // rare duplicate timestamp: exp(~14.3) amplification, redo alpha in fp32
                        const float* ar = aiW_f + (size_t)idx_i[il] * EMB;
                        const float* br = asW_f + (size_t)idx_j[jl] * EMB;
                        float adot = 0.0f;
                        for (int k = 0; k < EMB; ++k) adot += ar[k] * br[k];
                        alpha = adot;
                    }
                    // cross = alpha * exp_nat(-beta * ln(d)/ln5)
                    //       = alpha * exp2(-beta * log2(d) * (1/ln5))
                    float dl   = __builtin_amdgcn_logf(d + 1e-10f) * 0.6213349345596119f; // log2(d)/ln(5)
                    float beta = accB[mi][nj][r] + 1.0f;
                    beta = fminf(fmaxf(beta, 0.0f), 10.0f);
                    s += alpha * __builtin_amdgcn_exp2f(-beta * dl);
                }
                if (nj == 0) csum0 += s; else csum1 += s;
            }
        }
    }

    // ---- cross-lane / cross-wave reduction of column sums ----
    __syncthreads();
    if (tid < TILE) colsum[tid] = 0.0f;
    __syncthreads();
    csum0 += __shfl_xor(csum0, 32);
    csum1 += __shfl_xor(csum1, 32);
    if (l < 32) {
        atomicAdd(&colsum[wj * 64 + lane31], csum0);
        atomicAdd(&colsum[wj * 64 + 32 + lane31], csum1);
    }
    __syncthreads();

    if (tid < TILE) {
        int j = j0 + tid;
        float h = pbW[problems[b * SS + j]] + sbW[skills[b * SS + j]] + colsum[tid];
        out[b * SS + j] = 1.0f / (1.0f + __builtin_amdgcn_exp2f(-h * 1.4426950408889634f));
    }
}

extern "C" void kernel_launch(void* const* d_in, const int* in_sizes, int n_in,
                              void* d_out, int out_size, void* d_ws, size_t ws_size,
                              hipStream_t stream) {
    const int*   skills   = (const int*)d_in[0];
    const int*   problems = (const int*)d_in[1];
    const int*   times    = (const int*)d_in[2];
    const int*   labels   = (const int*)d_in[3];
    const float* aiW      = (const float*)d_in[4];  // alpha_inter_W [2000,256]
    const float* asW      = (const float*)d_in[5];  // alpha_skill_W [1000,256]
    const float* biW      = (const float*)d_in[6];  // beta_inter_W  [2000,256]
    const float* bsW      = (const float*)d_in[7];  // beta_skill_W  [1000,256]
    const float* pbW      = (const float*)d_in[8];  // problem_base_W [20000,1]
    const float* sbW      = (const float*)d_in[9];  // skill_base_W   [1000,1]
    float* out = (float*)d_out;
    __bf16* tab = (__bf16*)d_ws;   // needs 3 MB

    cvt_tables<<<(TOT_BF + 255) / 256, 256, 0, stream>>>(aiW, biW, asW, bsW, tab);
    hawkes_main<<<BB * NJT, 256, 0, stream>>>(skills, problems, times, labels,
                                              pbW, sbW, tab, aiW, asW, out);
}

// Round 3
// 263.706 us; speedup vs baseline: 1.3225x; 1.3225x over previous
//
#include <hip/hip_runtime.h>
#include <hip/hip_bf16.h>
#include <stdint.h>

#define NSK   1000
#define EMB   256
#define BB    32
#define SS    2048
#define TILE  128
#define NJT   (SS / TILE)     // 16
#define NUNIT (NJT * (NJT + 1) / 2)   // 136 tile-pairs per batch
#define BK    32              // K-chunk (double-buffered)
#define KS2   (BK / 16)       // 2 mfma k-steps per chunk
#define NCHUNK (EMB / BK)     // 8

typedef __bf16 bf16x8 __attribute__((ext_vector_type(8)));
typedef float  f32x16 __attribute__((ext_vector_type(16)));
typedef float  f32x4  __attribute__((ext_vector_type(4)));

// bf16 table layout in workspace (element offsets)
#define OFF_AI 0                  // alpha_inter  [2000][256]
#define OFF_BI (2 * NSK * EMB)    // beta_inter   [2000][256]
#define OFF_AS (4 * NSK * EMB)    // alpha_skill  [1000][256]
#define OFF_BS (5 * NSK * EMB)    // beta_skill   [1000][256]
#define TOT_BF (6 * NSK * EMB)    // 1,536,000 elements = 3 MB

// also zeroes the output accumulator (d_out doubles as hsum; poisoned each launch)
__global__ void cvt_tables(const float* __restrict__ ai, const float* __restrict__ bi,
                           const float* __restrict__ as_, const float* __restrict__ bs,
                           __bf16* __restrict__ ws, float* __restrict__ acc) {
    int i = blockIdx.x * 256 + threadIdx.x;
    if (i < BB * SS) acc[i] = 0.0f;
    if (i >= TOT_BF) return;
    float v;
    if (i < OFF_AS) v = (i < OFF_BI) ? ai[i] : bi[i - OFF_BI];
    else            v = (i < OFF_BS) ? as_[i - OFF_AS] : bs[i - OFF_BS];
    ws[i] = (__bf16)v;
}

#define ASYNC16(g, l)                                                              \
    __builtin_amdgcn_global_load_lds((__attribute__((address_space(1))) void*)(g), \
                                     (__attribute__((address_space(3))) void*)(l), \
                                     16, 0, 0)

// one WG = one (b, jt, it) tile-pair; partial colsums atomically added into acc
__global__ __launch_bounds__(256, 2) void hawkes_unit(
    const int* __restrict__ skills, const int* __restrict__ times,
    const int* __restrict__ labels, const __bf16* __restrict__ tab,
    const float* __restrict__ aiW_f, const float* __restrict__ asW_f,
    float* __restrict__ acc)
{
    // double-buffered fragment-order LDS:
    // elem(buf, mat, blk, ks) base = buf*16384 + mat*4096 + (blk*KS2+ks)*512  (+ lane*8 by DMA HW)
    __shared__ __align__(16) __bf16 sbuf[2 * 4 * TILE * BK];   // 64 KB
    __shared__ __align__(16) float  t_i[TILE];
    __shared__ __align__(16) float  t_j[TILE];
    __shared__ int   idx_i[TILE];
    __shared__ int   idx_j[TILE];
    __shared__ float colsum[TILE];

    const int u  = blockIdx.x;
    const int b  = u / NUNIT;
    const int p  = u - b * NUNIT;
    int jt = (int)((sqrtf(8.0f * (float)p + 1.0f) - 1.0f) * 0.5f);
    while ((jt + 1) * (jt + 2) / 2 <= p) ++jt;
    while (jt * (jt + 1) / 2 > p) --jt;
    const int it   = p - jt * (jt + 1) / 2;
    const bool diag = (it == jt);
    const int j0 = jt * TILE, i0 = it * TILE;

    const int tid = threadIdx.x;
    const int l   = tid & 63;
    const int w   = tid >> 6;
    const int wi  = w >> 1, wj = w & 1;       // 2x2 wave quadrants of 128x128
    const int lane31 = l & 31;
    const int khalf  = l >> 5;

    if (tid < TILE) {
        int j = j0 + tid;
        idx_j[tid] = skills[b * SS + j];
        t_j[tid]   = (float)times[b * SS + j] / 1000.0f;
        colsum[tid] = 0.0f;
    } else {
        int q = tid - TILE;
        int ii = i0 + q;
        idx_i[q] = skills[b * SS + ii] + labels[b * SS + ii] * NSK;
        t_i[q]   = (float)times[b * SS + ii] / 1000.0f;
    }
    __syncthreads();

    const float tj0 = t_j[wj * 64 + lane31];
    const float tj1 = t_j[wj * 64 + 32 + lane31];

    // per-wave staging: wave w stages matrix w (rows fixed for the whole unit)
    const __bf16* my_tab = (w == 0) ? (tab + OFF_AI)
                         : (w == 1) ? (tab + OFF_BI)
                         : (w == 2) ? (tab + OFF_AS)
                         :            (tab + OFF_BS);
    const int* my_idx = (w < 2) ? idx_i : idx_j;
    const __bf16* gbase[4];
#pragma unroll
    for (int m = 0; m < 4; ++m)
        gbase[m] = my_tab + (size_t)my_idx[m * 32 + lane31] * EMB + khalf * 8;

#define STAGE(c, cur)                                                         \
    do {                                                                      \
        __bf16* ldst = sbuf + (cur) * 16384 + w * 4096;                       \
        _Pragma("unroll")                                                     \
        for (int m = 0; m < 4; ++m)                                           \
            _Pragma("unroll")                                                 \
            for (int ks = 0; ks < KS2; ++ks)                                  \
                ASYNC16(gbase[m] + (c) * BK + ks * 16,                        \
                        ldst + (m * KS2 + ks) * 512);                         \
    } while (0)

    f32x16 accA[2][2], accB[2][2];
#pragma unroll
    for (int mi = 0; mi < 2; ++mi)
#pragma unroll
        for (int nj = 0; nj < 2; ++nj) { accA[mi][nj] = 0.0f; accB[mi][nj] = 0.0f; }

    STAGE(0, 0);

    for (int c = 0; c < NCHUNK; ++c) {
        const int cur = c & 1;
        __syncthreads();                 // drains chunk c's DMA only (prefetch not yet issued)
        if (c + 1 < NCHUNK) STAGE(c + 1, cur ^ 1);   // in flight during compute(c)

#pragma unroll
        for (int ks = 0; ks < KS2; ++ks) {
            bf16x8 fa[2], fb[2], ga[2], gb[2];
#pragma unroll
            for (int mi = 0; mi < 2; ++mi) {
                int mb = wi * 2 + mi;
                fa[mi] = *(const bf16x8*)(sbuf + cur * 16384 + 0 * 4096 + (mb * KS2 + ks) * 512 + l * 8);
                fb[mi] = *(const bf16x8*)(sbuf + cur * 16384 + 1 * 4096 + (mb * KS2 + ks) * 512 + l * 8);
            }
#pragma unroll
            for (int nj = 0; nj < 2; ++nj) {
                int nb = wj * 2 + nj;
                ga[nj] = *(const bf16x8*)(sbuf + cur * 16384 + 2 * 4096 + (nb * KS2 + ks) * 512 + l * 8);
                gb[nj] = *(const bf16x8*)(sbuf + cur * 16384 + 3 * 4096 + (nb * KS2 + ks) * 512 + l * 8);
            }
#pragma unroll
            for (int mi = 0; mi < 2; ++mi)
#pragma unroll
                for (int nj = 0; nj < 2; ++nj) {
                    accA[mi][nj] = __builtin_amdgcn_mfma_f32_32x32x16_bf16(fa[mi], ga[nj], accA[mi][nj], 0, 0, 0);
                    accB[mi][nj] = __builtin_amdgcn_mfma_f32_32x32x16_bf16(fb[mi], gb[nj], accB[mi][nj], 0, 0, 0);
                }
        }
    }

    // ---- elementwise + column partial sums ----
    // C/D layout (32x32): col = lane&31, row = (reg&3) + 8*(reg>>2) + 4*(lane>>5)
    float csum0 = 0.0f, csum1 = 0.0f;
#pragma unroll
    for (int mi = 0; mi < 2; ++mi) {
        const int rbase = (wi * 2 + mi) * 32 + 4 * khalf;
        f32x4 tiv[4];
#pragma unroll
        for (int q = 0; q < 4; ++q) tiv[q] = *(const f32x4*)(t_i + rbase + 8 * q);
#pragma unroll
        for (int nj = 0; nj < 2; ++nj) {
            const float tjv = (nj == 0) ? tj0 : tj1;
            const int   jl  = wj * 64 + nj * 32 + lane31;
            float s = 0.0f;
#pragma unroll
            for (int r = 0; r < 16; ++r) {
                const int q = r >> 2, e = r & 3;
                const int il = rbase + 8 * q + e;
                if (diag && il >= jl) continue;   // strict upper triangle (i < j)
                float d = fabsf(tiv[q][e] - tjv);
                float alpha = accA[mi][nj][r];
                if (d == 0.0f) {
                    // rare duplicate timestamp: huge kernel weight, redo alpha dot in fp32
                    const float* ar = aiW_f + (size_t)idx_i[il] * EMB;
                    const float* br = asW_f + (size_t)idx_j[jl] * EMB;
                    float adot = 0.0f;
                    for (int k = 0; k < EMB; ++k) adot += ar[k] * br[k];
                    alpha = adot;
                }
                // alpha * exp_nat(-beta*ln(d)/ln5) = alpha * exp2(-beta*log2(d)/ln5)
                float dl   = __builtin_amdgcn_logf(d + 1e-10f) * 0.6213349345596119f;
                float beta = accB[mi][nj][r] + 1.0f;
                beta = fminf(fmaxf(beta, 0.0f), 10.0f);
                s += alpha * __builtin_amdgcn_exp2f(-beta * dl);
            }
            if (nj == 0) csum0 += s; else csum1 += s;
        }
    }

    // ---- reduce to per-column sums, then one global atomic per column ----
    __syncthreads();   // colsum zero-init done in prologue; ensure all compute done
    csum0 += __shfl_xor(csum0, 32);
    csum1 += __shfl_xor(csum1, 32);
    if (l < 32) {
        atomicAdd(&colsum[wj * 64 + lane31], csum0);
        atomicAdd(&colsum[wj * 64 + 32 + lane31], csum1);
    }
    __syncthreads();
    if (tid < TILE)
        atomicAdd(&acc[b * SS + j0 + tid], colsum[tid]);
}

__global__ void hawkes_final(const int* __restrict__ skills, const int* __restrict__ problems,
                             const float* __restrict__ pbW, const float* __restrict__ sbW,
                             float* __restrict__ out) {
    int i = blockIdx.x * 256 + threadIdx.x;
    if (i >= BB * SS) return;
    float h = pbW[problems[i]] + sbW[skills[i]] + out[i];
    out[i] = 1.0f / (1.0f + __builtin_amdgcn_exp2f(-h * 1.4426950408889634f));
}

extern "C" void kernel_launch(void* const* d_in, const int* in_sizes, int n_in,
                              void* d_out, int out_size, void* d_ws, size_t ws_size,
                              hipStream_t stream) {
    const int*   skills   = (const int*)d_in[0];
    const int*   problems = (const int*)d_in[1];
    const int*   times    = (const int*)d_in[2];
    const int*   labels   = (const int*)d_in[3];
    const float* aiW      = (const float*)d_in[4];  // alpha_inter_W [2000,256]
    const float* asW      = (const float*)d_in[5];  // alpha_skill_W [1000,256]
    const float* biW      = (const float*)d_in[6];  // beta_inter_W  [2000,256]
    const float* bsW      = (const float*)d_in[7];  // beta_skill_W  [1000,256]
    const float* pbW      = (const float*)d_in[8];  // problem_base_W [20000,1]
    const float* sbW      = (const float*)d_in[9];  // skill_base_W   [1000,1]
    float* out = (float*)d_out;
    __bf16* tab = (__bf16*)d_ws;   // 3 MB

    cvt_tables<<<(TOT_BF + 255) / 256, 256, 0, stream>>>(aiW, biW, asW, bsW, tab, out);
    hawkes_unit<<<BB * NUNIT, 256, 0, stream>>>(skills, times, labels, tab, aiW, asW, out);
    hawkes_final<<<(BB * SS + 255) / 256, 256, 0, stream>>>(skills, problems, pbW, sbW, out);
}

// Round 4
// 220.284 us; speedup vs baseline: 1.5832x; 1.1971x over previous
//
#include <hip/hip_runtime.h>
#include <hip/hip_bf16.h>
#include <stdint.h>

#define NSK   1000
#define EMB   256
#define BB    32
#define SS    2048
#define TILE  128
#define NJT   (SS / TILE)             // 16
#define NUNIT (NJT * (NJT + 1) / 2)   // 136 tile-pairs per batch
#define BK    16                      // K-chunk (double-buffered)
#define NCHUNK (EMB / BK)             // 16

typedef __bf16 bf16x8 __attribute__((ext_vector_type(8)));
typedef float  f32x16 __attribute__((ext_vector_type(16)));
typedef float  f32x4  __attribute__((ext_vector_type(4)));

// bf16 table layout in workspace (element offsets)
#define OFF_AI 0                  // alpha_inter  [2000][256]
#define OFF_BI (2 * NSK * EMB)    // beta_inter   [2000][256]
#define OFF_AS (4 * NSK * EMB)    // alpha_skill  [1000][256]
#define OFF_BS (5 * NSK * EMB)    // beta_skill   [1000][256]
#define TOT_BF (6 * NSK * EMB)    // 1,536,000 elements = 3 MB

// also zeroes the output accumulator (d_out doubles as hsum; poisoned each launch)
__global__ void cvt_tables(const float* __restrict__ ai, const float* __restrict__ bi,
                           const float* __restrict__ as_, const float* __restrict__ bs,
                           __bf16* __restrict__ ws, float* __restrict__ acc) {
    int i = blockIdx.x * 256 + threadIdx.x;
    if (i < BB * SS) acc[i] = 0.0f;
    if (i >= TOT_BF) return;
    float v;
    if (i < OFF_AS) v = (i < OFF_BI) ? ai[i] : bi[i - OFF_BI];
    else            v = (i < OFF_BS) ? as_[i - OFF_AS] : bs[i - OFF_BS];
    ws[i] = (__bf16)v;
}

// rare duplicate-timestamp rescue: fp32 dot, single code copy (icache)
__device__ __attribute__((noinline)) float dot256(const float* __restrict__ a,
                                                  const float* __restrict__ b) {
    float s = 0.0f;
#pragma unroll 8
    for (int k = 0; k < EMB; ++k) s += a[k] * b[k];
    return s;
}

// one WG = one (b, jt, it) tile-pair; partial colsums atomically added into acc
__global__ __launch_bounds__(256, 2) void hawkes_unit(
    const int* __restrict__ skills, const int* __restrict__ times,
    const int* __restrict__ labels, const __bf16* __restrict__ tab,
    const float* __restrict__ aiW_f, const float* __restrict__ asW_f,
    float* __restrict__ acc)
{
    // double-buffered fragment-order LDS: buf*8192 + mat*2048 + mblk*512 + lane'*8
    // (elements; lane' = frag lane: row = lane'&31, khalf = lane'>>5)
    __shared__ __align__(16) __bf16 sbuf[2 * 4 * TILE * BK];   // 32 KB
    __shared__ __align__(16) float  t_i[TILE];
    __shared__ __align__(16) float  t_j[TILE];
    __shared__ int   idx_i[TILE];
    __shared__ int   idx_j[TILE];
    __shared__ float colsum[TILE];

    const int u  = blockIdx.x;
    const int b  = u / NUNIT;
    const int p  = u - b * NUNIT;
    int jt = (int)((sqrtf(8.0f * (float)p + 1.0f) - 1.0f) * 0.5f);
    while ((jt + 1) * (jt + 2) / 2 <= p) ++jt;
    while (jt * (jt + 1) / 2 > p) --jt;
    const int it   = p - jt * (jt + 1) / 2;
    const bool diag = (it == jt);
    const int j0 = jt * TILE, i0 = it * TILE;

    const int tid = threadIdx.x;
    const int l   = tid & 63;
    const int w   = tid >> 6;
    const int wi  = w >> 1, wj = w & 1;       // 2x2 wave quadrants of 128x128
    const int lane31 = l & 31;
    const int khalf  = l >> 5;

    if (tid < TILE) {
        int j = j0 + tid;
        idx_j[tid] = skills[b * SS + j];
        t_j[tid]   = (float)times[b * SS + j] / 1000.0f;
        colsum[tid] = 0.0f;
    } else {
        int q = tid - TILE;
        int ii = i0 + q;
        idx_i[q] = skills[b * SS + ii] + labels[b * SS + ii] * NSK;
        t_i[q]   = (float)times[b * SS + ii] / 1000.0f;
    }
    __syncthreads();

    const float tj0 = t_j[wj * 64 + lane31];
    const float tj1 = t_j[wj * 64 + 32 + lane31];

    // per-wave staging: wave w stages matrix w via coalesced VGPR loads + ds_write.
    // lane l handles row r = m*32 + (l>>1), k-half h = l&1 (pairs coalesce to 32B);
    // frag dest lane' = (l>>1) + 32*(l&1)  -> 2-way bank aliasing only (free).
    const __bf16* my_tab = (w == 0) ? (tab + OFF_AI)
                         : (w == 1) ? (tab + OFF_BI)
                         : (w == 2) ? (tab + OFF_AS)
                         :            (tab + OFF_BS);
    const int* my_idx = (w < 2) ? idx_i : idx_j;
    const __bf16* rowptr[4];
    int wel[4];   // LDS element offset within buffer for this lane's write
#pragma unroll
    for (int m = 0; m < 4; ++m) {
        int r = m * 32 + (l >> 1);
        rowptr[m] = my_tab + (size_t)my_idx[r] * EMB + (l & 1) * 8;
        wel[m] = w * 2048 + m * 512 + ((l >> 1) + 32 * (l & 1)) * 8;
    }

    bf16x8 sreg[4];
#define LOADC(c)                                                    \
    do { _Pragma("unroll")                                          \
        for (int m = 0; m < 4; ++m)                                 \
            sreg[m] = *(const bf16x8*)(rowptr[m] + (c) * BK);       \
    } while (0)
#define WRITEC(buf)                                                 \
    do { _Pragma("unroll")                                          \
        for (int m = 0; m < 4; ++m)                                 \
            *(bf16x8*)(sbuf + (buf) * 8192 + wel[m]) = sreg[m];     \
    } while (0)

    f32x16 accA[2][2], accB[2][2];
#pragma unroll
    for (int mi = 0; mi < 2; ++mi)
#pragma unroll
        for (int nj = 0; nj < 2; ++nj) { accA[mi][nj] = 0.0f; accB[mi][nj] = 0.0f; }

    LOADC(0);
    WRITEC(0);

    for (int c = 0; c < NCHUNK; ++c) {
        const int cur = c & 1;
        if (c + 1 < NCHUNK) LOADC(c + 1);      // in flight during compute(c)
        __syncthreads();                        // chunk c's ds_writes visible

        const __bf16* sb = sbuf + cur * 8192;
        bf16x8 fa[2], fb[2], ga[2], gb[2];
#pragma unroll
        for (int mi = 0; mi < 2; ++mi) {
            int mb = wi * 2 + mi;
            fa[mi] = *(const bf16x8*)(sb + 0 * 2048 + mb * 512 + l * 8);
            fb[mi] = *(const bf16x8*)(sb + 1 * 2048 + mb * 512 + l * 8);
        }
#pragma unroll
        for (int nj = 0; nj < 2; ++nj) {
            int nb = wj * 2 + nj;
            ga[nj] = *(const bf16x8*)(sb + 2 * 2048 + nb * 512 + l * 8);
            gb[nj] = *(const bf16x8*)(sb + 3 * 2048 + nb * 512 + l * 8);
        }
#pragma unroll
        for (int mi = 0; mi < 2; ++mi)
#pragma unroll
            for (int nj = 0; nj < 2; ++nj) {
                accA[mi][nj] = __builtin_amdgcn_mfma_f32_32x32x16_bf16(fa[mi], ga[nj], accA[mi][nj], 0, 0, 0);
                accB[mi][nj] = __builtin_amdgcn_mfma_f32_32x32x16_bf16(fb[mi], gb[nj], accB[mi][nj], 0, 0, 0);
            }

        if (c + 1 < NCHUNK) WRITEC(cur ^ 1);   // other buffer; next barrier publishes it
    }

    // ---- elementwise + column partial sums ----
    // C/D layout (32x32): col = lane&31, row = (reg&3) + 8*(reg>>2) + 4*(lane>>5)
    float csum0 = 0.0f, csum1 = 0.0f;
#pragma unroll
    for (int mi = 0; mi < 2; ++mi) {
        const int rbase = (wi * 2 + mi) * 32 + 4 * khalf;
        f32x4 tiv[4];
#pragma unroll
        for (int q = 0; q < 4; ++q) tiv[q] = *(const f32x4*)(t_i + rbase + 8 * q);
#pragma unroll
        for (int nj = 0; nj < 2; ++nj) {
            const float tjv = (nj == 0) ? tj0 : tj1;
            const int   jl  = wj * 64 + nj * 32 + lane31;
            float s = 0.0f;
#pragma unroll
            for (int r = 0; r < 16; ++r) {
                const int q = r >> 2, e = r & 3;
                const int il = rbase + 8 * q + e;
                if (diag && il >= jl) continue;   // strict upper triangle (i < j)
                float d = fabsf(tiv[q][e] - tjv);
                float alpha = accA[mi][nj][r];
                if (d == 0.0f)
                    alpha = dot256(aiW_f + (size_t)idx_i[il] * EMB,
                                   asW_f + (size_t)idx_j[jl] * EMB);
                // alpha * exp_nat(-beta*ln(d)/ln5) = alpha * exp2(-beta*log2(d)/ln5)
                float dl   = __builtin_amdgcn_logf(d + 1e-10f) * 0.6213349345596119f;
                float beta = accB[mi][nj][r] + 1.0f;
                beta = fminf(fmaxf(beta, 0.0f), 10.0f);
                s += alpha * __builtin_amdgcn_exp2f(-beta * dl);
            }
            if (nj == 0) csum0 += s; else csum1 += s;
        }
    }

    // ---- reduce to per-column sums, then one global atomic per column ----
    __syncthreads();
    csum0 += __shfl_xor(csum0, 32);
    csum1 += __shfl_xor(csum1, 32);
    if (l < 32) {
        atomicAdd(&colsum[wj * 64 + lane31], csum0);
        atomicAdd(&colsum[wj * 64 + 32 + lane31], csum1);
    }
    __syncthreads();
    if (tid < TILE)
        atomicAdd(&acc[b * SS + j0 + tid], colsum[tid]);
}

__global__ void hawkes_final(const int* __restrict__ skills, const int* __restrict__ problems,
                             const float* __restrict__ pbW, const float* __restrict__ sbW,
                             float* __restrict__ out) {
    int i = blockIdx.x * 256 + threadIdx.x;
    if (i >= BB * SS) return;
    float h = pbW[problems[i]] + sbW[skills[i]] + out[i];
    out[i] = 1.0f / (1.0f + __builtin_amdgcn_exp2f(-h * 1.4426950408889634f));
}

extern "C" void kernel_launch(void* const* d_in, const int* in_sizes, int n_in,
                              void* d_out, int out_size, void* d_ws, size_t ws_size,
                              hipStream_t stream) {
    const int*   skills   = (const int*)d_in[0];
    const int*   problems = (const int*)d_in[1];
    const int*   times    = (const int*)d_in[2];
    const int*   labels   = (const int*)d_in[3];
    const float* aiW      = (const float*)d_in[4];  // alpha_inter_W [2000,256]
    const float* asW      = (const float*)d_in[5];  // alpha_skill_W [1000,256]
    const float* biW      = (const float*)d_in[6];  // beta_inter_W  [2000,256]
    const float* bsW      = (const float*)d_in[7];  // beta_skill_W  [1000,256]
    const float* pbW      = (const float*)d_in[8];  // problem_base_W [20000,1]
    const float* sbW      = (const float*)d_in[9];  // skill_base_W   [1000,1]
    float* out = (float*)d_out;
    __bf16* tab = (__bf16*)d_ws;   // 3 MB

    cvt_tables<<<(TOT_BF + 255) / 256, 256, 0, stream>>>(aiW, biW, asW, bsW, tab, out);
    hawkes_unit<<<BB * NUNIT, 256, 0, stream>>>(skills, times, labels, tab, aiW, asW, out);
    hawkes_final<<<(BB * SS + 255) / 256, 256, 0, stream>>>(skills, problems, pbW, sbW, out);
}